// Round 2
// baseline (65.134 us; speedup 1.0000x reference)
//
#include <hip/hip_runtime.h>

#define N_IN   4096
#define N_NPB  64
#define COLS   16384
#define BATCH  128

typedef unsigned int  uint;
typedef unsigned short ushort;

// ---------------------------------------------------------------------------
// ws layout:
//   [0,        1 MiB)  xTb  : bf16 xT[4096][128]  (ushort)
//   [1 MiB,    5 MiB)  offs : uint [COLS][64]  pre-scaled byte offsets idx*256
//   [5 MiB,    9 MiB)  wef  : float[COLS][64]  dedup'd weights
// ---------------------------------------------------------------------------

static __device__ __forceinline__ ushort f2bf(float f) {
  uint u = __float_as_uint(f);
  u += 0x7fffu + ((u >> 16) & 1u);   // round-to-nearest-even
  return (ushort)(u >> 16);
}

// x [128][4096] f32 -> xTb [4096][128] bf16
__global__ __launch_bounds__(256) void transpose_bf16_kernel(
    const float* __restrict__ x, ushort* __restrict__ xTb) {
  __shared__ float tile[32][33];
  const int i0 = blockIdx.x * 32;
  const int b0 = blockIdx.y * 32;
  const int tx = threadIdx.x;   // 0..31
  const int ty = threadIdx.y;   // 0..7
#pragma unroll
  for (int j = 0; j < 32; j += 8)
    tile[ty + j][tx] = x[(b0 + ty + j) * N_IN + i0 + tx];
  __syncthreads();
#pragma unroll
  for (int j = 0; j < 32; j += 8)
    xTb[(i0 + ty + j) * BATCH + b0 + tx] = f2bf(tile[tx][ty + j]);
}

// Dedup (last-write-wins) + transpose idx/w into column-major offs/wef.
__global__ __launch_bounds__(256) void dedup_kernel(
    const float* __restrict__ w, const int* __restrict__ idx,
    uint* __restrict__ offs, float* __restrict__ wef) {
  __shared__ int   idx_s[N_NPB][65];
  __shared__ float w_s[N_NPB][65];
  const int c0  = blockIdx.x * 64;
  const int tid = threadIdx.x;

  for (int e = tid; e < N_NPB * 64; e += 256) {
    const int k = e >> 6, c = e & 63;
    idx_s[k][c] = idx[k * COLS + c0 + c];
    w_s[k][c]   = w[k * COLS + c0 + c];
  }
  __syncthreads();

  const int wave = tid >> 6;
  const int lane = tid & 63;   // lane == k

  for (int i = 0; i < 16; ++i) {
    const int cl    = wave * 16 + i;
    const int   my  = idx_s[lane][cl];
    const float mw  = w_s[lane][cl];
    bool dup = false;
#pragma unroll
    for (int j = 0; j < 64; ++j) {
      const int v = __shfl(my, j);
      dup = dup || (j > lane && v == my);
    }
    const int c = c0 + cl;
    offs[c * 64 + lane] = (uint)my * (BATCH * 2);  // byte offset into xTb
    wef[c * 64 + lane]  = dup ? 0.0f : mw;
  }
}

// Main: out[b,c] = sum_k wef[c][k] * xTb[offs[c][k]/256][b]
// 512 threads = 8 waves, 2 columns per wave, 16 columns per block.
// Lane l accumulates batches 2l and 2l+1 (one dword = 2 bf16 per load).
__global__ __launch_bounds__(512, 4) void branch_main_kernel(
    const uint* __restrict__ offs, const float* __restrict__ wef,
    const ushort* __restrict__ xTb, float* __restrict__ out) {
  __shared__ float res[BATCH][17];

  const int tid  = threadIdx.x;
  const int wave = tid >> 6;
  const int lane = tid & 63;
  const int c0   = blockIdx.x * 16;
  const char* xb = (const char*)xTb;
  const uint laneoff = (uint)lane << 2;

#pragma unroll
  for (int i = 0; i < 2; ++i) {
    // readfirstlane makes the column provably wave-uniform -> scalar loads
    const int cl = wave * 2 + i;
    const int c  = __builtin_amdgcn_readfirstlane(c0 + cl);
    const uint*  oc = offs + c * 64;
    const float* wc = wef  + c * 64;

    float a0 = 0.0f, a1 = 0.0f;
#pragma unroll
    for (int k = 0; k < N_NPB; ++k) {
      const uint  off = oc[k];
      const float wk  = wc[k];
      const uint  u   = *(const uint*)(xb + off + laneoff);
      const float lo  = __uint_as_float(u << 16);
      const float hi  = __uint_as_float(u & 0xffff0000u);
      a0 = fmaf(wk, lo, a0);
      a1 = fmaf(wk, hi, a1);
    }
    res[2 * lane][cl]     = a0;
    res[2 * lane + 1][cl] = a1;
  }
  __syncthreads();

  for (int e = tid; e < BATCH * 16; e += 512) {
    const int b = e >> 4, cc = e & 15;
    out[b * COLS + c0 + cc] = res[b][cc];
  }
}

extern "C" void kernel_launch(void* const* d_in, const int* in_sizes, int n_in,
                              void* d_out, int out_size, void* d_ws, size_t ws_size,
                              hipStream_t stream) {
  const float* x   = (const float*)d_in[0];
  const float* w   = (const float*)d_in[1];
  const int*   idx = (const int*)d_in[2];
  float* out = (float*)d_out;

  char* ws = (char*)d_ws;
  ushort* xTb  = (ushort*)(ws);
  uint*   offs = (uint*)(ws + (1u << 20));
  float*  wef  = (float*)(ws + (5u << 20));

  hipLaunchKernelGGL(transpose_bf16_kernel, dim3(N_IN / 32, BATCH / 32),
                     dim3(32, 8), 0, stream, x, xTb);
  hipLaunchKernelGGL(dedup_kernel, dim3(COLS / 64), dim3(256), 0, stream,
                     w, idx, offs, wef);
  hipLaunchKernelGGL(branch_main_kernel, dim3(COLS / 16), dim3(512), 0, stream,
                     offs, wef, xTb, out);
}

// Round 3
// 29.684 us; speedup vs baseline: 2.1942x; 2.1942x over previous
//
#include <hip/hip_runtime.h>

#define N_IN   4096
#define N_NPB  64
#define COLS   16384
#define BATCH  128

typedef unsigned int       uint;
typedef unsigned short     ushort;
typedef unsigned long long ulong64;

// ---------------------------------------------------------------------------
// ws layout:
//   [0,      1 MiB)       xTb  : bf16 xT[4096][128] (ushort)
//   [1 MiB,  1 MiB+128 K) keep : ushort[COLS][4] = 64-bit keep mask per column
// ---------------------------------------------------------------------------

static __device__ __forceinline__ ushort f2bf(float f) {
  uint u = __float_as_uint(f);
  u += 0x7fffu + ((u >> 16) & 1u);   // round-to-nearest-even
  return (ushort)(u >> 16);
}

// x [128][4096] f32 -> xTb [4096][128] bf16
__global__ __launch_bounds__(256) void transpose_bf16_kernel(
    const float* __restrict__ x, ushort* __restrict__ xTb) {
  __shared__ float tile[32][33];
  const int i0 = blockIdx.x * 32;
  const int b0 = blockIdx.y * 32;
  const int tx = threadIdx.x;   // 0..31
  const int ty = threadIdx.y;   // 0..7
#pragma unroll
  for (int j = 0; j < 32; j += 8)
    tile[ty + j][tx] = x[(b0 + ty + j) * N_IN + i0 + tx];
  __syncthreads();
#pragma unroll
  for (int j = 0; j < 32; j += 8)
    xTb[(i0 + ty + j) * BATCH + b0 + tx] = f2bf(tile[tx][ty + j]);
}

// ---------------------------------------------------------------------------
// keepmask: bit k of keep[c] = 1 iff no k' > k has idx[k'][c] == idx[k][c].
// One thread per (column, 16-k group). idx column in registers, all indices
// compile-time (templated k-base) so nothing spills to scratch.
// ---------------------------------------------------------------------------
template <int KBASE>
static __device__ __forceinline__ uint compute_bits(const int* __restrict__ ip) {
  int v[64 - KBASE];
#pragma unroll
  for (int k = 0; k < 64 - KBASE; ++k) v[k] = ip[(KBASE + k) * COLS];
  uint bits = 0;
#pragma unroll
  for (int j = 0; j < 16; ++j) {
    uint m = 0xffffffffu;
#pragma unroll
    for (int kp = j + 1; kp < 64 - KBASE; ++kp)
      m = min(m, (uint)(v[j] ^ v[kp]));
    bits |= (m != 0u) ? (1u << j) : 0u;
  }
  return bits;
}

__global__ __launch_bounds__(256, 4) void keepmask_kernel(
    const int* __restrict__ idx, ushort* __restrict__ keep16) {
  const int tid = threadIdx.x;
  const int kg  = __builtin_amdgcn_readfirstlane(tid >> 6);  // wave-uniform
  const int c   = blockIdx.x * 64 + (tid & 63);
  const int* ip = idx + c;
  uint bits;
  if      (kg == 0) bits = compute_bits<0>(ip);
  else if (kg == 1) bits = compute_bits<16>(ip);
  else if (kg == 2) bits = compute_bits<32>(ip);
  else              bits = compute_bits<48>(ip);
  keep16[c * 4 + kg] = (ushort)bits;
}

// ---------------------------------------------------------------------------
// Main: out[b,c] = sum_k wk * xTb[idx[k][c]][b]
// 256 threads = 4 waves, 4 columns per wave (16/block). Within a wave:
//   g  = lane>>4 : which of the wave's 4 columns
//   b8 = lane&15 : batch octet -> one dwordx4 = 8 bf16 batches per lane.
// Masked weights staged once in LDS, read per-k as broadcast ds_read.
// ---------------------------------------------------------------------------
__global__ __launch_bounds__(256, 4) void branch_main_kernel(
    const float* __restrict__ w, const int* __restrict__ idx,
    const ulong64* __restrict__ keep, const ushort* __restrict__ xTb,
    float* __restrict__ out) {
  __shared__ float wlds[N_NPB][17];
  __shared__ float res[BATCH][17];

  const int tid = threadIdx.x;
  const int c0  = blockIdx.x * 16;

  // Stage masked weights (coalesced w reads; keep mask hoisted per thread).
  {
    const int cl = tid & 15;
    const ulong64 km = keep[c0 + cl];
    const int k0 = tid >> 4;   // 0..15
#pragma unroll
    for (int p = 0; p < 4; ++p) {
      const int k = k0 + p * 16;
      const float wv = w[k * COLS + c0 + cl];
      wlds[k][cl] = ((km >> k) & 1ull) ? wv : 0.0f;
    }
  }
  __syncthreads();

  const int wave = tid >> 6;
  const int lane = tid & 63;
  const int g    = lane >> 4;
  const int b8   = lane & 15;
  const int cl   = wave * 4 + g;
  const int c    = c0 + cl;

  // This lane's column index list -> 64 VGPRs (compile-time indexed).
  int rows[64];
  {
    const int* ip = idx + c;
#pragma unroll
    for (int k = 0; k < 64; ++k) rows[k] = ip[k * COLS];
  }

  float a0 = 0.f, a1 = 0.f, a2 = 0.f, a3 = 0.f;
  float a4 = 0.f, a5 = 0.f, a6 = 0.f, a7 = 0.f;
  const char* xb = (const char*)xTb;
  const uint  bo = (uint)b8 * 16;

#pragma unroll
  for (int k = 0; k < 64; ++k) {
    const uint4 u = *(const uint4*)(xb + (((uint)rows[k] << 8) + bo));
    const float wv = wlds[k][cl];
    a0 = fmaf(wv, __uint_as_float(u.x << 16),          a0);
    a1 = fmaf(wv, __uint_as_float(u.x & 0xffff0000u),  a1);
    a2 = fmaf(wv, __uint_as_float(u.y << 16),          a2);
    a3 = fmaf(wv, __uint_as_float(u.y & 0xffff0000u),  a3);
    a4 = fmaf(wv, __uint_as_float(u.z << 16),          a4);
    a5 = fmaf(wv, __uint_as_float(u.z & 0xffff0000u),  a5);
    a6 = fmaf(wv, __uint_as_float(u.w << 16),          a6);
    a7 = fmaf(wv, __uint_as_float(u.w & 0xffff0000u),  a7);
  }

  res[b8 * 8 + 0][cl] = a0;
  res[b8 * 8 + 1][cl] = a1;
  res[b8 * 8 + 2][cl] = a2;
  res[b8 * 8 + 3][cl] = a3;
  res[b8 * 8 + 4][cl] = a4;
  res[b8 * 8 + 5][cl] = a5;
  res[b8 * 8 + 6][cl] = a6;
  res[b8 * 8 + 7][cl] = a7;
  __syncthreads();

  // Coalesced output: 16 consecutive floats per 16-lane group.
  for (int e = tid; e < BATCH * 16; e += 256) {
    out[(e >> 4) * COLS + c0 + (e & 15)] = res[e >> 4][e & 15];
  }
}

extern "C" void kernel_launch(void* const* d_in, const int* in_sizes, int n_in,
                              void* d_out, int out_size, void* d_ws, size_t ws_size,
                              hipStream_t stream) {
  const float* x   = (const float*)d_in[0];
  const float* w   = (const float*)d_in[1];
  const int*   idx = (const int*)d_in[2];
  float* out = (float*)d_out;

  char* ws = (char*)d_ws;
  ushort*  xTb    = (ushort*)(ws);
  ushort*  keep16 = (ushort*)(ws + (1u << 20));
  ulong64* keep   = (ulong64*)(ws + (1u << 20));

  hipLaunchKernelGGL(transpose_bf16_kernel, dim3(N_IN / 32, BATCH / 32),
                     dim3(32, 8), 0, stream, x, xTb);
  hipLaunchKernelGGL(keepmask_kernel, dim3(COLS / 64), dim3(256), 0, stream,
                     idx, keep16);
  hipLaunchKernelGGL(branch_main_kernel, dim3(COLS / 16), dim3(256), 0, stream,
                     w, idx, keep, xTb, out);
}

// Round 4
// 23.909 us; speedup vs baseline: 2.7243x; 1.2416x over previous
//
#include <hip/hip_runtime.h>

#define N_IN   4096
#define N_NPB  64
#define COLS   16384
#define BATCH  128

typedef unsigned int       uint;
typedef unsigned short     ushort;
typedef unsigned long long u64;
typedef __attribute__((ext_vector_type(2))) _Float16 h2;

// ---------------------------------------------------------------------------
// ws layout:
//   [0,      1 MiB)       xTh  : f16 xT[4096][128] (ushort)
//   [1 MiB,  1 MiB+128 K) keep : ushort[COLS][4] = 64-bit keep mask per column
// ---------------------------------------------------------------------------

// keepmask helper: bit j (of this 16-k group) = 1 iff no later k' duplicates.
template <int KBASE>
static __device__ __forceinline__ uint compute_bits(const int* __restrict__ ip) {
  int v[64 - KBASE];
#pragma unroll
  for (int k = 0; k < 64 - KBASE; ++k) v[k] = ip[(KBASE + k) * COLS];
  uint bits = 0;
#pragma unroll
  for (int j = 0; j < 16; ++j) {
    uint m = 0xffffffffu;
#pragma unroll
    for (int kp = j + 1; kp < 64 - KBASE; ++kp)
      m = min(m, (uint)(v[j] ^ v[kp]));
    bits |= (m != 0u) ? (1u << j) : 0u;
  }
  return bits;
}

// Fused prep: blocks [0,512) transpose x -> f16 xT; blocks [512,768) keepmask.
__global__ __launch_bounds__(256, 4) void prep_kernel(
    const float* __restrict__ x, const int* __restrict__ idx,
    ushort* __restrict__ xTh, ushort* __restrict__ keep16) {
  const int bid = blockIdx.x;
  const int tid = threadIdx.x;
  if (bid < 512) {
    // transpose tile: 32 input-features x 32 batches
    __shared__ float tile[32][33];
    const int i0 = (bid & 127) * 32;
    const int b0 = (bid >> 7) * 32;
    const int tx = tid & 31;
    const int ty = tid >> 5;    // 0..7
#pragma unroll
    for (int j = 0; j < 32; j += 8)
      tile[ty + j][tx] = x[(b0 + ty + j) * N_IN + i0 + tx];
    __syncthreads();
#pragma unroll
    for (int j = 0; j < 32; j += 8)
      xTh[(i0 + ty + j) * BATCH + b0 + tx] =
          __builtin_bit_cast(ushort, (_Float16)tile[tx][ty + j]);
  } else {
    const int kg = __builtin_amdgcn_readfirstlane(tid >> 6);  // wave-uniform
    const int c  = (bid - 512) * 64 + (tid & 63);
    const int* ip = idx + c;
    uint bits;
    if      (kg == 0) bits = compute_bits<0>(ip);
    else if (kg == 1) bits = compute_bits<16>(ip);
    else if (kg == 2) bits = compute_bits<32>(ip);
    else              bits = compute_bits<48>(ip);
    keep16[c * 4 + kg] = (ushort)bits;
  }
}

// ---------------------------------------------------------------------------
// Main: out[b,c] = sum_k wk * xTh[idx[k][c]][b]
// 256 threads = 4 waves, 4 columns/wave. lane: g=lane>>4 (column), b8=lane&15
// (batch octet, one dwordx4 = 8 f16 batches). Per-(k,c) data pre-packed in
// LDS as one qword: lo32 = idx<<8 byte offset, hi32 = duplicated f16 weight.
// ---------------------------------------------------------------------------
__global__ __launch_bounds__(256, 8) void branch_main_kernel(
    const float* __restrict__ w, const int* __restrict__ idx,
    const u64* __restrict__ keep, const ushort* __restrict__ xTh,
    float* __restrict__ out) {
  __shared__ u64   pk[N_NPB][16];
  __shared__ float res2[16][129];

  const int tid = threadIdx.x;
  const int c0  = blockIdx.x * 16;

  // Stage packed (offset | dup'd f16 weight) entries; 4 per thread, coalesced.
  {
    const int cl = tid & 15;
    const int k0 = (tid >> 4) * 4;
    const u64 km = keep[c0 + cl];
#pragma unroll
    for (int p = 0; p < 4; ++p) {
      const int k   = k0 + p;
      const int row = idx[k * COLS + c0 + cl];
      float wv      = w[k * COLS + c0 + cl];
      wv = ((km >> k) & 1ull) ? wv : 0.0f;
      const uint hb = (uint)__builtin_bit_cast(ushort, (_Float16)wv);
      pk[k][cl] = ((u64)((hb << 16) | hb) << 32) | ((u64)((uint)row << 8));
    }
  }
  __syncthreads();

  const int wave = tid >> 6;
  const int lane = tid & 63;
  const int g    = lane >> 4;
  const int b8   = lane & 15;
  const int cl   = wave * 4 + g;

  h2 a0 = (h2)0.0f, a1 = (h2)0.0f, a2 = (h2)0.0f, a3 = (h2)0.0f;
  const char* xb = (const char*)xTh;
  const uint  bo = (uint)b8 * 16;

#pragma unroll
  for (int k = 0; k < N_NPB; ++k) {
    const u64  e   = pk[k][cl];                       // ds_read_b64, broadcast
    const uint off = (uint)e;                         // idx*256
    const h2   wh  = __builtin_bit_cast(h2, (uint)(e >> 32));
    const uint4 u  = *(const uint4*)(xb + off + bo);  // 8 f16 batches
    a0 += __builtin_bit_cast(h2, u.x) * wh;           // v_pk_fma_f16
    a1 += __builtin_bit_cast(h2, u.y) * wh;
    a2 += __builtin_bit_cast(h2, u.z) * wh;
    a3 += __builtin_bit_cast(h2, u.w) * wh;
  }

  // Stage per-column-major results: 8 consecutive floats -> 2x ds_write_b128.
  {
    float* r = &res2[cl][b8 * 8];
    r[0] = (float)a0.x; r[1] = (float)a0.y;
    r[2] = (float)a1.x; r[3] = (float)a1.y;
    r[4] = (float)a2.x; r[5] = (float)a2.y;
    r[6] = (float)a3.x; r[7] = (float)a3.y;
  }
  __syncthreads();

  for (int e = tid; e < BATCH * 16; e += 256) {
    const int b = e >> 4, cc = e & 15;
    out[b * COLS + c0 + cc] = res2[cc][b];
  }
}

extern "C" void kernel_launch(void* const* d_in, const int* in_sizes, int n_in,
                              void* d_out, int out_size, void* d_ws, size_t ws_size,
                              hipStream_t stream) {
  const float* x   = (const float*)d_in[0];
  const float* w   = (const float*)d_in[1];
  const int*   idx = (const int*)d_in[2];
  float* out = (float*)d_out;

  char* ws = (char*)d_ws;
  ushort* xTh    = (ushort*)(ws);
  ushort* keep16 = (ushort*)(ws + (1u << 20));
  u64*    keep   = (u64*)(ws + (1u << 20));

  hipLaunchKernelGGL(prep_kernel, dim3(512 + COLS / 64), dim3(256), 0, stream,
                     x, idx, xTh, keep16);
  hipLaunchKernelGGL(branch_main_kernel, dim3(COLS / 16), dim3(256), 0, stream,
                     w, idx, keep, xTh, out);
}